// Round 1
// baseline (239.118 us; speedup 1.0000x reference)
//
#include <hip/hip_runtime.h>
#include <cstddef>

#define EPS 1e-5f
static constexpr int Bn = 64, Cn = 64, Hn = 56, Wn = 56, HWn = Hn * Wn; // 3136

// ---------------------------------------------------------------------------
// K1: node0 = relu(bn1(conv1x1(x, w1)))   [B,C,H,W], K=64
// Block: 256 thr, tile = 64 pixels x 64 channels. Thread = (pixel lane, 16-o group).
// w1/bn reads are wave-uniform -> s_load (scalar cache), LDS used only for x tile.
// ---------------------------------------------------------------------------
__global__ __launch_bounds__(256) void k1_conv1(
    const float* __restrict__ x, const float* __restrict__ w1,
    const float* __restrict__ bg, const float* __restrict__ bb,
    const float* __restrict__ bm, const float* __restrict__ bv,
    float* __restrict__ node0)
{
    __shared__ float xs[64][64];
    const int tid = threadIdx.x;
    const int b = blockIdx.x / 49;
    const int pix0 = (blockIdx.x % 49) * 64;
    const float* xb = x + (size_t)b * (Cn * HWn) + pix0;
    #pragma unroll
    for (int i = 0; i < 16; ++i) {
        int flat = tid + i * 256;
        int c = flat >> 6, p = flat & 63;
        xs[c][p] = xb[(size_t)c * HWn + p];
    }
    __syncthreads();
    const int lane = tid & 63;
    const int og = __builtin_amdgcn_readfirstlane(tid >> 6) * 16;
    float acc[16];
    #pragma unroll
    for (int i = 0; i < 16; ++i) acc[i] = 0.f;
    #pragma unroll 4
    for (int c = 0; c < 64; ++c) {
        float a = xs[c][lane];
        #pragma unroll
        for (int i = 0; i < 16; ++i)
            acc[i] = fmaf(w1[(og + i) * 64 + c], a, acc[i]);
    }
    float* nb = node0 + (size_t)b * (Cn * HWn) + pix0;
    #pragma unroll
    for (int i = 0; i < 16; ++i) {
        int o = og + i;
        float sc = bg[o] * rsqrtf(bv[o] + EPS);
        float sh = bb[o] - bm[o] * sc;
        float val = fmaf(acc[i], sc, sh);
        nb[(size_t)o * HWn + lane] = val > 0.f ? val : 0.f;
    }
}

// ---------------------------------------------------------------------------
// K2: node2 = avgpool3(node0); node3 = maxpool5(node0) + maxpool3(node2)
// One wave per (b,c) plane (4096 planes). Lane = column. Horizontal windows via
// shuffles, vertical windows via register rolling. node0 >= 0 so 0-pad == -inf pad.
// ---------------------------------------------------------------------------
__global__ __launch_bounds__(256) void k2_pools(
    const float* __restrict__ node0, float* __restrict__ d2, float* __restrict__ d3)
{
    const int lane = threadIdx.x & 63;
    const int plane = blockIdx.x * 4 + (threadIdx.x >> 6);
    const float* src = node0 + (size_t)plane * HWn;
    float* o2 = d2 + (size_t)plane * HWn;
    float* o3 = d3 + (size_t)plane * HWn;
    const int col = lane;
    const bool act = (col < Wn);

    float hs1 = 0.f, hs2 = 0.f;                        // hsum rows r-1, r-2
    float hm5a = 0.f, hm5b = 0.f, hm5c = 0.f, hm5d = 0.f; // hmax5 rows r-4..r-1
    float nh1 = 0.f, nh2 = 0.f;                        // h3(node2) rows r-2, r-3

    for (int r = 0; r < 58; ++r) {
        float v = 0.f;
        if (r < Hn && act) v = src[r * Wn + col];
        float lf = __shfl_up(v, 1);   if (lane == 0)  lf = 0.f;
        float rt = __shfl_down(v, 1); if (lane == 63) rt = 0.f;
        float hsum = lf + v + rt;
        float hm3 = fmaxf(fmaxf(lf, v), rt);
        float l2 = __shfl_up(hm3, 1);   if (lane == 0)  l2 = 0.f;
        float r2 = __shfl_down(hm3, 1); if (lane == 63) r2 = 0.f;
        float hm5 = fmaxf(fmaxf(l2, hm3), r2);

        // node2 row (r-1): rows r-2..r of hsum
        float a2 = (hs2 + hs1 + hsum) * (1.f / 9.f);
        hs2 = hs1; hs1 = hsum;
        if (r < 1 || r > 56) a2 = 0.f;   // out-of-range node2 row -> zero pad

        // maxpool5 row (r-2): hmax5 rows r-4..r
        float m5 = fmaxf(fmaxf(fmaxf(hm5a, hm5b), fmaxf(hm5c, hm5d)), hm5);
        hm5a = hm5b; hm5b = hm5c; hm5c = hm5d; hm5d = hm5;

        // maxpool3(node2) row (r-2): h3(node2) rows r-3..r-1
        float al = __shfl_up(a2, 1);   if (lane == 0)  al = 0.f;
        float ar = __shfl_down(a2, 1); if (lane == 63) ar = 0.f;
        float nh = fmaxf(fmaxf(al, a2), ar);
        float m3a = fmaxf(fmaxf(nh2, nh1), nh);
        nh2 = nh1; nh1 = nh;

        if (act) {
            if (r >= 1 && r <= 56) o2[(r - 1) * Wn + col] = a2;
            if (r >= 2)            o3[(r - 2) * Wn + col] = m5 + m3a;
        }
    }
}

// ---------------------------------------------------------------------------
// K3: out = relu(bn2(conv1x1(cat[node2,node3], w2)))   K=128
// Same structure as K1; 32 KB LDS tile for the 128-channel cat.
// ---------------------------------------------------------------------------
__global__ __launch_bounds__(256) void k3_conv2(
    const float* __restrict__ n2, const float* __restrict__ n3,
    const float* __restrict__ w2,
    const float* __restrict__ bg, const float* __restrict__ bb,
    const float* __restrict__ bm, const float* __restrict__ bv,
    float* __restrict__ out)
{
    __shared__ float cs[128][64];
    const int tid = threadIdx.x;
    const int b = blockIdx.x / 49;
    const int pix0 = (blockIdx.x % 49) * 64;
    const float* s2 = n2 + (size_t)b * (Cn * HWn) + pix0;
    const float* s3 = n3 + (size_t)b * (Cn * HWn) + pix0;
    #pragma unroll
    for (int i = 0; i < 16; ++i) {
        int flat = tid + i * 256;
        int c = flat >> 6, p = flat & 63;
        cs[c][p]      = s2[(size_t)c * HWn + p];
        cs[c + 64][p] = s3[(size_t)c * HWn + p];
    }
    __syncthreads();
    const int lane = tid & 63;
    const int og = __builtin_amdgcn_readfirstlane(tid >> 6) * 16;
    float acc[16];
    #pragma unroll
    for (int i = 0; i < 16; ++i) acc[i] = 0.f;
    #pragma unroll 4
    for (int c = 0; c < 128; ++c) {
        float a = cs[c][lane];
        #pragma unroll
        for (int i = 0; i < 16; ++i)
            acc[i] = fmaf(w2[(og + i) * 128 + c], a, acc[i]);
    }
    float* ob = out + (size_t)b * (Cn * HWn) + pix0;
    #pragma unroll
    for (int i = 0; i < 16; ++i) {
        int o = og + i;
        float sc = bg[o] * rsqrtf(bv[o] + EPS);
        float sh = bb[o] - bm[o] * sc;
        float val = fmaf(acc[i], sc, sh);
        ob[(size_t)o * HWn + lane] = val > 0.f ? val : 0.f;
    }
}

extern "C" void kernel_launch(void* const* d_in, const int* in_sizes, int n_in,
                              void* d_out, int out_size, void* d_ws, size_t ws_size,
                              hipStream_t stream)
{
    const float* x   = (const float*)d_in[0];
    const float* w1  = (const float*)d_in[1];
    const float* w2  = (const float*)d_in[2];
    const float* b1g = (const float*)d_in[3];
    const float* b1b = (const float*)d_in[4];
    const float* b1m = (const float*)d_in[5];
    const float* b1v = (const float*)d_in[6];
    const float* b2g = (const float*)d_in[7];
    const float* b2b = (const float*)d_in[8];
    const float* b2m = (const float*)d_in[9];
    const float* b2v = (const float*)d_in[10];

    float* out = (float*)d_out;
    float* node0 = out;                         // d_out doubles as node0 scratch
    float* n2 = (float*)d_ws;                   // [B,C,H,W] fp32
    float* n3 = n2 + (size_t)Bn * Cn * HWn;     // [B,C,H,W] fp32

    k1_conv1<<<dim3(Bn * 49), dim3(256), 0, stream>>>(x, w1, b1g, b1b, b1m, b1v, node0);
    k2_pools<<<dim3(Bn * Cn / 4), dim3(256), 0, stream>>>(node0, n2, n3);
    k3_conv2<<<dim3(Bn * 49), dim3(256), 0, stream>>>(n2, n3, w2, b2g, b2b, b2m, b2v, out);
}

// Round 2
// 204.755 us; speedup vs baseline: 1.1678x; 1.1678x over previous
//
#include <hip/hip_runtime.h>
#include <cstddef>

#define EPS 1e-5f
static constexpr int Bn = 64, Cn = 64, Hn = 56, Wn = 56, HWn = Hn * Wn; // 3136

typedef __attribute__((ext_vector_type(8))) short short8;
typedef __attribute__((ext_vector_type(4))) float floatx4;

__device__ __forceinline__ unsigned short f2bf(float f) {
    unsigned u = __float_as_uint(f);
    return (unsigned short)((u + 0x7fffu + ((u >> 16) & 1u)) >> 16); // RNE
}
__device__ __forceinline__ float bf2f(unsigned short s) {
    return __uint_as_float(((unsigned)s) << 16);
}

// ---------------------------------------------------------------------------
// K1: node0[p][c] (pixel-major bf16) = relu(bn1(conv1x1(x, w1)))
// Per wave: D[o=16][p=16] tiles, A=w1 regs, B=x direct global, K=64 (2 mfma/o-tile).
// Epilogue repacked via padded LDS -> contiguous dwordx4 global stores.
// ---------------------------------------------------------------------------
__global__ __launch_bounds__(256) void k1_conv1(
    const float* __restrict__ x, const float* __restrict__ w1,
    const float* __restrict__ bg, const float* __restrict__ bb,
    const float* __restrict__ bm, const float* __restrict__ bv,
    unsigned short* __restrict__ node0)
{
    __shared__ unsigned short pack[64 * 88];  // 64 px rows, stride 88 (176B, 16B-aligned, 2-way max)
    __shared__ float scs[64], shs[64];
    const int tid = threadIdx.x;
    if (tid < 64) {
        float sc = bg[tid] * rsqrtf(bv[tid] + EPS);
        scs[tid] = sc;
        shs[tid] = bb[tid] - bm[tid] * sc;
    }
    const int lane = tid & 63;
    const int wv   = tid >> 6;
    const int m    = lane & 15;
    const int quad = lane >> 4;

    // A-frags: w1[o][k], lane holds row o = t*16+m, k = kk*32 + quad*8 + j
    short8 afr[4][2];
    #pragma unroll
    for (int t = 0; t < 4; ++t) {
        #pragma unroll
        for (int kk = 0; kk < 2; ++kk) {
            const float* wp = w1 + (t * 16 + m) * 64 + kk * 32 + quad * 8;
            floatx4 f0 = *(const floatx4*)wp;
            floatx4 f1 = *(const floatx4*)(wp + 4);
            short8 s;
            s[0] = (short)f2bf(f0[0]); s[1] = (short)f2bf(f0[1]);
            s[2] = (short)f2bf(f0[2]); s[3] = (short)f2bf(f0[3]);
            s[4] = (short)f2bf(f1[0]); s[5] = (short)f2bf(f1[1]);
            s[6] = (short)f2bf(f1[2]); s[7] = (short)f2bf(f1[3]);
            afr[t][kk] = s;
        }
    }
    __syncthreads();

    for (int tt = 0; tt < 4; ++tt) {
        const long P0 = (long)blockIdx.x * 256 + tt * 64; // 64-px group, never crosses image (3136%64==0)
        const int b = (int)(P0 / HWn);
        const int p = (int)(P0 - (long)b * HWn) + wv * 16 + m;

        floatx4 acc[4];
        #pragma unroll
        for (int t = 0; t < 4; ++t) acc[t] = (floatx4){0.f, 0.f, 0.f, 0.f};

        #pragma unroll
        for (int kk = 0; kk < 2; ++kk) {
            short8 bfr;
            #pragma unroll
            for (int j = 0; j < 8; ++j) {
                int c = kk * 32 + quad * 8 + j;
                bfr[j] = (short)f2bf(x[(size_t)(b * 64 + c) * HWn + p]);
            }
            #pragma unroll
            for (int t = 0; t < 4; ++t)
                acc[t] = __builtin_amdgcn_mfma_f32_16x16x32_bf16(afr[t][kk], bfr, acc[t], 0, 0, 0);
        }

        __syncthreads();  // protect pack[] from previous iteration's readers
        #pragma unroll
        for (int t = 0; t < 4; ++t) {
            #pragma unroll
            for (int i = 0; i < 4; ++i) {
                int o = t * 16 + quad * 4 + i;
                float v = fmaf(acc[t][i], scs[o], shs[o]);
                v = v > 0.f ? v : 0.f;
                pack[(wv * 16 + m) * 88 + o] = f2bf(v);
            }
        }
        __syncthreads();
        // contiguous 8 KB store: thread -> 2x 16B chunks
        #pragma unroll
        for (int it = 0; it < 2; ++it) {
            int cid = it * 256 + tid;
            int px = cid >> 3, part = cid & 7;
            short8 vv = *(const short8*)(pack + px * 88 + part * 8);
            *(short8*)(node0 + (size_t)(P0 + px) * 64 + part * 8) = vv;
        }
    }
}

// ---------------------------------------------------------------------------
// K2: cat[p][0:64]=avgpool3(node0), cat[p][64:128]=maxpool5(node0)+maxpool3(avg)
// Block = (b, 8-row band), 512 thr: wave = 8-ch chunk, lane = column.
// Rolling vertical rings; horizontal via 5-col loads; shuffles only for n2-h3.
// ---------------------------------------------------------------------------
__global__ __launch_bounds__(512) void k2_pools(
    const unsigned short* __restrict__ node0, unsigned short* __restrict__ cat)
{
    const int tid = threadIdx.x;
    const int lane = tid & 63;
    const int chunk = tid >> 6;            // 0..7 -> channels [chunk*8, +8)
    const int b = blockIdx.x / 7;
    const int band = blockIdx.x % 7;
    const int lo = band * 8, hi = lo + 8;
    const int col = lane;
    const bool act = col < Wn;
    const unsigned short* base = node0 + (size_t)b * HWn * 64 + chunk * 8;
    unsigned short* cbase = cat + (size_t)b * HWn * 128 + chunk * 8;

    float hs1[8], hs2[8], h5a[8], h5b[8], h5c[8], h5d[8], nh1[8], nh2[8];
    #pragma unroll
    for (int j = 0; j < 8; ++j) {
        hs1[j] = hs2[j] = 0.f;
        h5a[j] = h5b[j] = h5c[j] = h5d[j] = 0.f;
        nh1[j] = nh2[j] = 0.f;
    }

    for (int r = lo - 2; r <= hi + 1; ++r) {
        float v[5][8];
        #pragma unroll
        for (int d = 0; d < 5; ++d) {
            int cc = col + d - 2;
            bool ok = act && ((unsigned)cc < (unsigned)Wn) && ((unsigned)r < (unsigned)Hn);
            if (ok) {
                short8 ld = *(const short8*)(base + (size_t)(r * Wn + cc) * 64);
                #pragma unroll
                for (int j = 0; j < 8; ++j) v[d][j] = bf2f((unsigned short)ld[j]);
            } else {
                #pragma unroll
                for (int j = 0; j < 8; ++j) v[d][j] = 0.f;
            }
        }
        float hsum[8], hm5[8], a2[8], m5[8], nh[8], m3[8];
        const int r2 = r - 1, r3 = r - 2;
        const bool v2 = (unsigned)r2 < (unsigned)Hn;
        #pragma unroll
        for (int j = 0; j < 8; ++j) {
            hsum[j] = v[1][j] + v[2][j] + v[3][j];
            hm5[j] = fmaxf(fmaxf(fmaxf(v[0][j], v[1][j]), fmaxf(v[2][j], v[3][j])), v[4][j]);
            a2[j] = v2 ? (hs2[j] + hs1[j] + hsum[j]) * (1.f / 9.f) : 0.f;
            hs2[j] = hs1[j]; hs1[j] = hsum[j];
            m5[j] = fmaxf(fmaxf(fmaxf(h5a[j], h5b[j]), fmaxf(h5c[j], h5d[j])), hm5[j]);
            h5a[j] = h5b[j]; h5b[j] = h5c[j]; h5c[j] = h5d[j]; h5d[j] = hm5[j];
        }
        #pragma unroll
        for (int j = 0; j < 8; ++j) {
            float al = __shfl_up(a2[j], 1);   if (lane == 0)  al = 0.f;
            float ar = __shfl_down(a2[j], 1); if (lane == 63) ar = 0.f;
            nh[j] = fmaxf(fmaxf(al, a2[j]), ar);
            m3[j] = fmaxf(fmaxf(nh2[j], nh1[j]), nh[j]);
            nh2[j] = nh1[j]; nh1[j] = nh[j];
        }
        if (act && r2 >= lo && r2 < hi) {
            short8 st;
            #pragma unroll
            for (int j = 0; j < 8; ++j) st[j] = (short)f2bf(a2[j]);
            *(short8*)(cbase + (size_t)(r2 * Wn + col) * 128) = st;
        }
        if (act && r3 >= lo && r3 < hi) {
            short8 st;
            #pragma unroll
            for (int j = 0; j < 8; ++j) st[j] = (short)f2bf(m5[j] + m3[j]);
            *(short8*)(cbase + (size_t)(r3 * Wn + col) * 128 + 64) = st;
        }
    }
}

// ---------------------------------------------------------------------------
// K3: out[b][o][p] fp32 = relu(bn2(conv1x1(cat, w2))), K=128, O=64.
// No LDS staging: B-frags are 16B-contiguous dwordx4 from pixel-major cat;
// A=w2 in regs; D cols = pixels -> coalesced dword stores.
// ---------------------------------------------------------------------------
__global__ __launch_bounds__(256) void k3_conv2(
    const unsigned short* __restrict__ cat, const float* __restrict__ w2,
    const float* __restrict__ bg, const float* __restrict__ bb,
    const float* __restrict__ bm, const float* __restrict__ bv,
    float* __restrict__ out)
{
    __shared__ float scs[64], shs[64];
    const int tid = threadIdx.x;
    if (tid < 64) {
        float sc = bg[tid] * rsqrtf(bv[tid] + EPS);
        scs[tid] = sc;
        shs[tid] = bb[tid] - bm[tid] * sc;
    }
    const int lane = tid & 63;
    const int wv   = tid >> 6;
    const int m    = lane & 15;
    const int quad = lane >> 4;

    short8 afr[4][4];
    #pragma unroll
    for (int t = 0; t < 4; ++t) {
        #pragma unroll
        for (int kk = 0; kk < 4; ++kk) {
            const float* wp = w2 + (t * 16 + m) * 128 + kk * 32 + quad * 8;
            floatx4 f0 = *(const floatx4*)wp;
            floatx4 f1 = *(const floatx4*)(wp + 4);
            short8 s;
            s[0] = (short)f2bf(f0[0]); s[1] = (short)f2bf(f0[1]);
            s[2] = (short)f2bf(f0[2]); s[3] = (short)f2bf(f0[3]);
            s[4] = (short)f2bf(f1[0]); s[5] = (short)f2bf(f1[1]);
            s[6] = (short)f2bf(f1[2]); s[7] = (short)f2bf(f1[3]);
            afr[t][kk] = s;
        }
    }
    __syncthreads();

    const int wgid = blockIdx.x * 4 + wv;
    #pragma unroll
    for (int tt = 0; tt < 4; ++tt) {
        const int tile = wgid * 4 + tt;              // 16-px tile, tiles never cross images
        const int bI = tile / 196;
        const size_t Pl = (size_t)tile * 16 + m;     // global pixel-linear = b*3136 + p
        const int p = (int)(Pl - (size_t)bI * HWn);

        floatx4 acc[4];
        #pragma unroll
        for (int t = 0; t < 4; ++t) acc[t] = (floatx4){0.f, 0.f, 0.f, 0.f};

        #pragma unroll
        for (int kk = 0; kk < 4; ++kk) {
            short8 bfr = *(const short8*)(cat + Pl * 128 + kk * 32 + quad * 8);
            #pragma unroll
            for (int t = 0; t < 4; ++t)
                acc[t] = __builtin_amdgcn_mfma_f32_16x16x32_bf16(afr[t][kk], bfr, acc[t], 0, 0, 0);
        }
        #pragma unroll
        for (int t = 0; t < 4; ++t) {
            #pragma unroll
            for (int i = 0; i < 4; ++i) {
                int o = t * 16 + quad * 4 + i;
                float v = fmaf(acc[t][i], scs[o], shs[o]);
                v = v > 0.f ? v : 0.f;
                out[(size_t)bI * (64 * HWn) + (size_t)o * HWn + p] = v;
            }
        }
    }
}

extern "C" void kernel_launch(void* const* d_in, const int* in_sizes, int n_in,
                              void* d_out, int out_size, void* d_ws, size_t ws_size,
                              hipStream_t stream)
{
    const float* x   = (const float*)d_in[0];
    const float* w1  = (const float*)d_in[1];
    const float* w2  = (const float*)d_in[2];
    const float* b1g = (const float*)d_in[3];
    const float* b1b = (const float*)d_in[4];
    const float* b1m = (const float*)d_in[5];
    const float* b1v = (const float*)d_in[6];
    const float* b2g = (const float*)d_in[7];
    const float* b2b = (const float*)d_in[8];
    const float* b2m = (const float*)d_in[9];
    const float* b2v = (const float*)d_in[10];

    float* out = (float*)d_out;
    unsigned short* node0 = (unsigned short*)d_ws;              // [B*HW][64] bf16, 25.7 MB
    unsigned short* cat   = node0 + (size_t)Bn * HWn * 64;      // [B*HW][128] bf16, 51.4 MB

    k1_conv1<<<dim3(784), dim3(256), 0, stream>>>(x, w1, b1g, b1b, b1m, b1v, node0);
    k2_pools<<<dim3(Bn * 7), dim3(512), 0, stream>>>(node0, cat);
    k3_conv2<<<dim3(784), dim3(256), 0, stream>>>(cat, w2, b2g, b2b, b2m, b2v, out);
}